// Round 2
// baseline (1206.069 us; speedup 1.0000x reference)
//
#include <hip/hip_runtime.h>
#include <hip/hip_bf16.h>

#define D 128
#define EPS 1e-5f

// ---------- CSR build (once per launch) ----------
__global__ __launch_bounds__(256) void k_count(const int* __restrict__ row,
                                               int* __restrict__ cnt, int E) {
  int e = blockIdx.x * 256 + threadIdx.x;
  if (e < E) atomicAdd(&cnt[row[e]], 1);
}

__global__ __launch_bounds__(1024) void k_scan(const int* __restrict__ cnt,
                                               int* __restrict__ rptr, int N, int E) {
  __shared__ int sh[1024];
  int t = threadIdx.x;
  int CH = (N + 1023) / 1024;
  int lo = t * CH, hi = min(N, lo + CH);
  int s = 0;
  for (int i = lo; i < hi; ++i) s += cnt[i];
  sh[t] = s;
  __syncthreads();
  for (int off = 1; off < 1024; off <<= 1) {
    int v = (t >= off) ? sh[t - off] : 0;
    __syncthreads();
    sh[t] += v;
    __syncthreads();
  }
  int run = (t > 0) ? sh[t - 1] : 0;
  for (int i = lo; i < hi; ++i) { rptr[i] = run; run += cnt[i]; }
  if (t == 0) rptr[N] = E;
}

__global__ __launch_bounds__(256) void k_scatter(
    const int* __restrict__ row, const int* __restrict__ col,
    const int* __restrict__ rptr, int* __restrict__ cur,
    int* __restrict__ rowS, int* __restrict__ colS, int E) {
  int e = blockIdx.x * 256 + threadIdx.x;
  if (e < E) {
    int r = row[e];
    int p = rptr[r] + atomicAdd(&cur[r], 1);
    rowS[p] = r;
    colS[p] = col[e];
  }
}

__global__ __launch_bounds__(256) void k_rev(const int* __restrict__ rowS,
                                             const int* __restrict__ colS,
                                             const int* __restrict__ rptr,
                                             int* __restrict__ rev, int E) {
  int p = blockIdx.x * 256 + threadIdx.x;
  if (p >= E) return;
  int r = rowS[p], c = colS[p];
  int q1 = rptr[c + 1];
  int rv = -1;
  for (int q = rptr[c]; q < q1; ++q)
    if (colS[q] == r) { rv = q; break; }
  rev[p] = rv;
}

// ---------- attention ----------
__global__ __launch_bounds__(256) void k_norm(const float* __restrict__ h,
                                              float* __restrict__ nrm, int N) {
  int i = blockIdx.x * 4 + (threadIdx.x >> 6);
  int lane = threadIdx.x & 63;
  if (i >= N) return;
  float2 a = ((const float2*)(h + (size_t)i * D))[lane];
  double v = (double)a.x * a.x + (double)a.y * a.y;
  for (int off = 32; off > 0; off >>= 1) v += __shfl_down(v, off);
  if (lane == 0) nrm[i] = (float)sqrt(v);
}

__global__ __launch_bounds__(256) void k_sim(
    const float* __restrict__ h, const float* __restrict__ nrm,
    const int* __restrict__ rowS, const int* __restrict__ colS,
    float* __restrict__ simS, int E) {
  int p = blockIdx.x * 4 + (threadIdx.x >> 6);
  int lane = threadIdx.x & 63;
  if (p >= E) return;
  int r = rowS[p], c = colS[p];
  float2 a = ((const float2*)(h + (size_t)r * D))[lane];
  float2 b = ((const float2*)(h + (size_t)c * D))[lane];
  double v = (double)a.x * b.x + (double)a.y * b.y;
  for (int off = 32; off > 0; off >>= 1) v += __shfl_down(v, off);
  if (lane == 0) {
    float sm = (float)v / (nrm[r] * nrm[c]);
    simS[p] = (sm < 0.1f) ? 0.0f : sm;
  }
}

// row-l1 normalize in place: att = sim / (rs>0 ? rs : 1)
__global__ __launch_bounds__(256) void k_att(const int* __restrict__ rptr,
                                             float* __restrict__ simS, int N) {
  int i = blockIdx.x * 256 + threadIdx.x;
  if (i >= N) return;
  int p0 = rptr[i], p1 = rptr[i + 1];
  float rs = 0.f;
  for (int p = p0; p < p1; ++p) rs += simS[p];
  float d = (rs > 0.f) ? rs : 1.f;
  for (int p = p0; p < p1; ++p) simS[p] /= d;
}

// drop mask + w_e = exp(att) + deg -> w_diag, per node
__global__ __launch_bounds__(256) void k_drop(
    const int* __restrict__ rptr, const float* __restrict__ attS,
    const int* __restrict__ rev, float* __restrict__ weS,
    float* __restrict__ wdia, const float* __restrict__ dWp,
    const float* __restrict__ dbp, int N) {
  int i = blockIdx.x * 256 + threadIdx.x;
  if (i >= N) return;
  float w0 = dWp[0], w1 = dWp[1], bd = dbp[0];
  int p0 = rptr[i], p1 = rptr[i + 1];
  int deg = 0;
  for (int p = p0; p < p1; ++p) {
    float a = attS[p];
    int rv = rev[p];
    float ar = (rv >= 0) ? attS[rv] : 0.f;
    float x = a * w0 + ar * w1 + bd;
    float sc = (x >= 0.f) ? 1.f / (1.f + expf(-x)) : expf(x) / (1.f + expf(x));
    float am = (sc > 0.5f) ? a : 0.f;
    weS[p] = (am != 0.f) ? expf(am) : 0.f;
    deg += (am != 0.f) ? 1 : 0;
  }
  wdia[i] = expf(1.0f / (float)(deg + 1));
}

// ---------- s = h @ W (f32, LDS tiled, BM=32, W staged in 2 halves) ----------
__global__ __launch_bounds__(256) void k_gemm(const float* __restrict__ A,
                                              const float* __restrict__ W,
                                              float* __restrict__ S, int N) {
  __shared__ float Ws[64 * D];
  __shared__ float As[32 * D];
  int t = threadIdx.x;
  int i0 = blockIdx.x * 32;
  for (int ch = 0; ch < 4; ++ch) {
    int q = t + 256 * ch;              // [0,1024) float4 slots of A tile
    int r = q >> 5, c4 = q & 31;
    int gi = i0 + r;
    float4 a4 = (gi < N) ? ((const float4*)(A + (size_t)gi * D))[c4]
                         : make_float4(0.f, 0.f, 0.f, 0.f);
    ((float4*)As)[q] = a4;
  }
  int tx = t & 31, ty = t >> 5;
  float acc[4][4] = {};
  for (int ph = 0; ph < 2; ++ph) {
    __syncthreads();
    for (int ch = 0; ch < 8; ++ch) {
      int q = t + 256 * ch;            // [0,2048) float4 slots of 64 W rows
      ((float4*)Ws)[q] = ((const float4*)(W + (size_t)ph * 64 * D))[q];
    }
    __syncthreads();
    for (int k = 0; k < 64; ++k) {
      float4 b = ((const float4*)&Ws[k * D])[tx];
#pragma unroll
      for (int r = 0; r < 4; ++r) {
        float a = As[(ty * 4 + r) * D + (ph * 64 + k)];
        acc[r][0] += a * b.x; acc[r][1] += a * b.y;
        acc[r][2] += a * b.z; acc[r][3] += a * b.w;
      }
    }
  }
  for (int r = 0; r < 4; ++r) {
    int gi = i0 + ty * 4 + r;
    if (gi < N) {
      float4 o = make_float4(acc[r][0], acc[r][1], acc[r][2], acc[r][3]);
      ((float4*)(S + (size_t)gi * D))[tx] = o;
    }
  }
}

// ---------- aggregate + self + bias, then LN+ReLU (MODE 0) or log_softmax (MODE 1)
template <int MODE>
__global__ __launch_bounds__(128) void k_combine(
    const float* __restrict__ s, const float* __restrict__ weS,
    const float* __restrict__ wdia, const int* __restrict__ rptr,
    const int* __restrict__ colS, const float* __restrict__ bias,
    const float* __restrict__ g, const float* __restrict__ be,
    float* __restrict__ outF, int N) {
  int i = blockIdx.x;
  int d = threadIdx.x;                 // 0..127
  __shared__ float red[2];
  int p0 = rptr[i], p1 = rptr[i + 1];
  float acc = 0.f;
  for (int p = p0; p < p1; ++p) {
    float w = weS[p];
    if (w != 0.f) {
      int c = colS[p];
      acc += w * s[(size_t)c * D + d];
    }
  }
  float v = acc + wdia[i] * s[(size_t)i * D + d] + bias[d];
  int lane = d & 63, wid = d >> 6;
  if (MODE == 0) {
    float t = v;
    for (int off = 32; off > 0; off >>= 1) t += __shfl_down(t, off);
    if (lane == 0) red[wid] = t;
    __syncthreads();
    float mu = (red[0] + red[1]) * (1.f / 128.f);
    __syncthreads();
    float dv = v - mu;
    t = dv * dv;
    for (int off = 32; off > 0; off >>= 1) t += __shfl_down(t, off);
    if (lane == 0) red[wid] = t;
    __syncthreads();
    float var = (red[0] + red[1]) * (1.f / 128.f);
    float y = dv * rsqrtf(var + EPS) * g[d] + be[d];
    outF[(size_t)i * D + d] = fmaxf(y, 0.f);
  } else {
    float t = v;
    for (int off = 32; off > 0; off >>= 1) t = fmaxf(t, __shfl_down(t, off));
    if (lane == 0) red[wid] = t;
    __syncthreads();
    float m = fmaxf(red[0], red[1]);
    __syncthreads();
    t = expf(v - m);
    for (int off = 32; off > 0; off >>= 1) t += __shfl_down(t, off);
    if (lane == 0) red[wid] = t;
    __syncthreads();
    float l = logf(red[0] + red[1]);
    outF[(size_t)i * D + d] = v - m - l;
  }
}

extern "C" void kernel_launch(void* const* d_in, const int* in_sizes, int n_in,
                              void* d_out, int out_size, void* d_ws, size_t ws_size,
                              hipStream_t stream) {
  const float* x   = (const float*)d_in[0];
  const float* W0  = (const float*)d_in[1];
  const float* b0  = (const float*)d_in[2];
  const float* W1  = (const float*)d_in[3];
  const float* b1  = (const float*)d_in[4];
  const float* g1  = (const float*)d_in[5];
  const float* be1 = (const float*)d_in[6];
  const float* g2  = (const float*)d_in[7];
  const float* be2 = (const float*)d_in[8];
  const float* dW  = (const float*)d_in[9];
  const float* db  = (const float*)d_in[10];
  const int* row   = (const int*)d_in[11];
  const int* col   = (const int*)d_in[12];
  int N = in_sizes[0] / D;
  int E = in_sizes[11];
  float* out = (float*)d_out;

  float* base = (float*)d_ws;
  size_t off = 0;
  auto alloc = [&](size_t elems) {
    float* p = base + off;
    off += (elems + 3) & ~(size_t)3;   // keep 16B alignment
    return p;
  };
  size_t N128 = (size_t)N * D;
  int Npad = (N + 3) & ~3;
  float* hA   = alloc(N128);           // layer-0 output
  float* hB   = alloc(N128);           // layer-1 output
  float* s    = alloc(N128);           // h @ W
  int*   rowS = (int*)alloc(E);
  int*   colS = (int*)alloc(E);
  int*   rev  = (int*)alloc(E);
  float* simS = alloc(E);              // sim, then att in place
  float* weS  = alloc(E);
  int*   cc   = (int*)alloc((size_t)2 * Npad);  // cnt | cur
  int*   cnt  = cc;
  int*   cur  = cc + Npad;
  int*   rptr = (int*)alloc(N + 1);
  float* nrm  = alloc(N);
  float* wdia = alloc(N);
  (void)ws_size; (void)n_in; (void)out_size;

  hipMemsetAsync(cc, 0, (size_t)2 * Npad * sizeof(int), stream);
  k_count<<<(E + 255) / 256, 256, 0, stream>>>(row, cnt, E);
  k_scan<<<1, 1024, 0, stream>>>(cnt, rptr, N, E);
  k_scatter<<<(E + 255) / 256, 256, 0, stream>>>(row, col, rptr, cur, rowS, colS, E);
  k_rev<<<(E + 255) / 256, 256, 0, stream>>>(rowS, colS, rptr, rev, E);

  auto layer = [&](const float* hin, float* hout, const float* Wf,
                   const float* bf, const float* gf, const float* bef, int mode) {
    k_norm<<<(N + 3) / 4, 256, 0, stream>>>(hin, nrm, N);
    k_sim<<<(E + 3) / 4, 256, 0, stream>>>(hin, nrm, rowS, colS, simS, E);
    k_att<<<(N + 255) / 256, 256, 0, stream>>>(rptr, simS, N);
    k_drop<<<(N + 255) / 256, 256, 0, stream>>>(rptr, simS, rev, weS, wdia, dW, db, N);
    k_gemm<<<(N + 31) / 32, 256, 0, stream>>>(hin, Wf, s, N);
    if (mode == 0)
      k_combine<0><<<N, 128, 0, stream>>>(s, weS, wdia, rptr, colS, bf, gf, bef,
                                          hout, N);
    else
      k_combine<1><<<N, 128, 0, stream>>>(s, weS, wdia, rptr, colS, bf, gf, bef,
                                          hout, N);
  };
  // layer 0: x -> hA (W0, b0, ln1)
  layer(x, hA, W0, b0, g1, be1, 0);
  // layer 1: hA -> hB (W1, b1, ln2)
  layer(hA, hB, W1, b1, g2, be2, 0);
  // final: hB -> out (W1, b1, log_softmax)  [source bug reuses convs[-2]]
  layer(hB, out, W1, b1, nullptr, nullptr, 1);
}

// Round 3
// 897.236 us; speedup vs baseline: 1.3442x; 1.3442x over previous
//
#include <hip/hip_runtime.h>
#include <hip/hip_bf16.h>

#define D 128
#define EPS 1e-5f

// ---------- CSR build (once per launch) ----------
__global__ __launch_bounds__(256) void k_count(const int* __restrict__ row,
                                               int* __restrict__ cnt, int E) {
  int e = blockIdx.x * 256 + threadIdx.x;
  if (e < E) atomicAdd(&cnt[row[e]], 1);
}

__global__ __launch_bounds__(1024) void k_scan(const int* __restrict__ cnt,
                                               int* __restrict__ rptr, int N, int E) {
  __shared__ int sh[1024];
  int t = threadIdx.x;
  int CH = (N + 1023) / 1024;
  int lo = t * CH, hi = min(N, lo + CH);
  int s = 0;
  for (int i = lo; i < hi; ++i) s += cnt[i];
  sh[t] = s;
  __syncthreads();
  for (int off = 1; off < 1024; off <<= 1) {
    int v = (t >= off) ? sh[t - off] : 0;
    __syncthreads();
    sh[t] += v;
    __syncthreads();
  }
  int run = (t > 0) ? sh[t - 1] : 0;
  for (int i = lo; i < hi; ++i) { rptr[i] = run; run += cnt[i]; }
  if (t == 0) rptr[N] = E;
}

__global__ __launch_bounds__(256) void k_scatter(
    const int* __restrict__ row, const int* __restrict__ col,
    const int* __restrict__ rptr, int* __restrict__ cur,
    int* __restrict__ rowS, int* __restrict__ colS, int E) {
  int e = blockIdx.x * 256 + threadIdx.x;
  if (e < E) {
    int r = row[e];
    int p = rptr[r] + atomicAdd(&cur[r], 1);
    rowS[p] = r;
    colS[p] = col[e];
  }
}

__global__ __launch_bounds__(256) void k_rev(const int* __restrict__ rowS,
                                             const int* __restrict__ colS,
                                             const int* __restrict__ rptr,
                                             int* __restrict__ rev, int E) {
  int p = blockIdx.x * 256 + threadIdx.x;
  if (p >= E) return;
  int r = rowS[p], c = colS[p];
  int q1 = rptr[c + 1];
  int rv = -1;
  for (int q = rptr[c]; q < q1; ++q)
    if (colS[q] == r) { rv = q; break; }
  rev[p] = rv;
}

// ---------- attention ----------
// hn[i] = h[i] / ||h[i]||  (one row per 32 lanes, float4 per lane)
__global__ __launch_bounds__(256) void k_normalize(const float* __restrict__ h,
                                                   float* __restrict__ hn, int N) {
  int i = blockIdx.x * 8 + (threadIdx.x >> 5);
  int sub = threadIdx.x & 31;
  if (i >= N) return;
  float4 a = ((const float4*)(h + (size_t)i * D))[sub];
  float v = a.x * a.x + a.y * a.y + a.z * a.z + a.w * a.w;
  for (int off = 16; off > 0; off >>= 1) v += __shfl_down(v, off, 32);
  v = __shfl(v, 0, 32);
  float r = 1.0f / sqrtf(v);
  float4 o = make_float4(a.x * r, a.y * r, a.z * r, a.w * r);
  ((float4*)(hn + (size_t)i * D))[sub] = o;
}

// sim = dot(hn[r], hn[c]); threshold at 0.1.  32 lanes/edge, f32 tree reduce.
__global__ __launch_bounds__(256) void k_sim(
    const float* __restrict__ hn, const int* __restrict__ rowS,
    const int* __restrict__ colS, float* __restrict__ simS, int E) {
  int p = blockIdx.x * 8 + (threadIdx.x >> 5);
  int sub = threadIdx.x & 31;
  if (p >= E) return;
  int r = rowS[p], c = colS[p];
  float4 a = ((const float4*)(hn + (size_t)r * D))[sub];
  float4 b = ((const float4*)(hn + (size_t)c * D))[sub];
  float v = a.x * b.x + a.y * b.y + a.z * b.z + a.w * b.w;
  for (int off = 16; off > 0; off >>= 1) v += __shfl_down(v, off, 32);
  if (sub == 0) simS[p] = (v < 0.1f) ? 0.0f : v;
}

// per-node row sums of sim -> rs_eff (rs>0 ? rs : 1)
__global__ __launch_bounds__(256) void k_rowsum(const int* __restrict__ rptr,
                                                const float* __restrict__ simS,
                                                float* __restrict__ rsE, int N) {
  int i = blockIdx.x * 256 + threadIdx.x;
  if (i >= N) return;
  int p0 = rptr[i], p1 = rptr[i + 1];
  float rs = 0.f;
  for (int p = p0; p < p1; ++p) rs += simS[p];
  rsE[i] = (rs > 0.f) ? rs : 1.f;
}

// drop mask + w_e = exp(att) + deg -> w_diag, per node.
// att = sim/rs (division kept to match reference rounding exactly).
__global__ __launch_bounds__(256) void k_drop(
    const int* __restrict__ rptr, const float* __restrict__ simS,
    const float* __restrict__ rsE, const int* __restrict__ colS,
    const int* __restrict__ rev, float* __restrict__ weS,
    float* __restrict__ wdia, const float* __restrict__ dWp,
    const float* __restrict__ dbp, int N) {
  int i = blockIdx.x * 256 + threadIdx.x;
  if (i >= N) return;
  float w0 = dWp[0], w1 = dWp[1], bd = dbp[0];
  float ri = rsE[i];
  int p0 = rptr[i], p1 = rptr[i + 1];
  int deg = 0;
  for (int p = p0; p < p1; ++p) {
    float a = simS[p] / ri;
    int rv = rev[p];
    float ar = (rv >= 0) ? simS[rv] / rsE[colS[p]] : 0.f;
    float x = a * w0 + ar * w1 + bd;
    float sc = (x >= 0.f) ? 1.f / (1.f + expf(-x)) : expf(x) / (1.f + expf(x));
    float am = (sc > 0.5f) ? a : 0.f;
    weS[p] = (am != 0.f) ? expf(am) : 0.f;
    deg += (am != 0.f) ? 1 : 0;
  }
  wdia[i] = expf(1.0f / (float)(deg + 1));
}

// ---------- s = h @ W (f32, BM=64, W staged in 2 halves, float4 LDS reads) ----
__global__ __launch_bounds__(256) void k_gemm(const float* __restrict__ A,
                                              const float* __restrict__ W,
                                              float* __restrict__ S, int N) {
  __shared__ float Ws[64 * D];   // 32 KB
  __shared__ float As[64 * D];   // 32 KB
  int t = threadIdx.x;
  int i0 = blockIdx.x * 64;
  // stage A tile (64x128) as float4
  for (int ch = 0; ch < 8; ++ch) {
    int q = t + 256 * ch;              // [0,2048) float4 slots
    int r = q >> 5, c4 = q & 31;
    int gi = i0 + r;
    float4 a4 = (gi < N) ? ((const float4*)(A + (size_t)gi * D))[c4]
                         : make_float4(0.f, 0.f, 0.f, 0.f);
    ((float4*)As)[q] = a4;
  }
  int tx = t & 31, ty = t >> 5;        // tx: col float4 group, ty: 8-row group
  float acc[8][4] = {};
  for (int ph = 0; ph < 2; ++ph) {
    __syncthreads();
    for (int ch = 0; ch < 8; ++ch) {
      int q = t + 256 * ch;            // 64 W rows of this phase
      ((float4*)Ws)[q] = ((const float4*)(W + (size_t)ph * 64 * D))[q];
    }
    __syncthreads();
    for (int kk = 0; kk < 16; ++kk) {  // 4 k's per iter
      float4 a4[8];
#pragma unroll
      for (int r = 0; r < 8; ++r)
        a4[r] = ((const float4*)(As + (ty * 8 + r) * D))[ph * 16 + kk];
      float4 b0 = ((const float4*)(Ws + (kk * 4 + 0) * D))[tx];
      float4 b1 = ((const float4*)(Ws + (kk * 4 + 1) * D))[tx];
      float4 b2 = ((const float4*)(Ws + (kk * 4 + 2) * D))[tx];
      float4 b3 = ((const float4*)(Ws + (kk * 4 + 3) * D))[tx];
#pragma unroll
      for (int r = 0; r < 8; ++r) {
        float4 a = a4[r];
        acc[r][0] += a.x * b0.x + a.y * b1.x + a.z * b2.x + a.w * b3.x;
        acc[r][1] += a.x * b0.y + a.y * b1.y + a.z * b2.y + a.w * b3.y;
        acc[r][2] += a.x * b0.z + a.y * b1.z + a.z * b2.z + a.w * b3.z;
        acc[r][3] += a.x * b0.w + a.y * b1.w + a.z * b2.w + a.w * b3.w;
      }
    }
  }
#pragma unroll
  for (int r = 0; r < 8; ++r) {
    int gi = i0 + ty * 8 + r;
    if (gi < N) {
      float4 o = make_float4(acc[r][0], acc[r][1], acc[r][2], acc[r][3]);
      ((float4*)(S + (size_t)gi * D))[tx] = o;
    }
  }
}

// ---------- aggregate + self + bias, then LN+ReLU (MODE 0) or log_softmax (MODE 1)
// LDS-staged edge list with zero-compaction + 4-way unrolled gather.
template <int MODE>
__global__ __launch_bounds__(128) void k_combine(
    const float* __restrict__ s, const float* __restrict__ weS,
    const float* __restrict__ wdia, const int* __restrict__ rptr,
    const int* __restrict__ colS, const float* __restrict__ bias,
    const float* __restrict__ g, const float* __restrict__ be,
    float* __restrict__ outF, int N) {
  int i = blockIdx.x;
  int d = threadIdx.x;                 // 0..127
  __shared__ float red[2];
  __shared__ float sw[128];
  __shared__ int sc[128];
  __shared__ int scnt;
  int p0 = rptr[i], p1 = rptr[i + 1];
  float acc = 0.f;
  for (int base = p0; base < p1; base += 128) {
    int m = min(128, p1 - base);
    if (d == 0) scnt = 0;
    __syncthreads();
    if (d < m) {
      float w = weS[base + d];
      if (w != 0.f) {
        int sl = atomicAdd(&scnt, 1);
        sw[sl] = w;
        sc[sl] = colS[base + d];
      }
    }
    __syncthreads();
    int K = scnt;
    int j = 0;
    for (; j + 4 <= K; j += 4) {
      int c0 = sc[j], c1 = sc[j + 1], c2 = sc[j + 2], c3 = sc[j + 3];
      float w0 = sw[j], w1 = sw[j + 1], w2 = sw[j + 2], w3 = sw[j + 3];
      float s0 = s[(size_t)c0 * D + d];
      float s1 = s[(size_t)c1 * D + d];
      float s2 = s[(size_t)c2 * D + d];
      float s3 = s[(size_t)c3 * D + d];
      acc += w0 * s0;
      acc += w1 * s1;
      acc += w2 * s2;
      acc += w3 * s3;
    }
    for (; j < K; ++j) acc += sw[j] * s[(size_t)sc[j] * D + d];
    __syncthreads();
  }
  float v = acc + wdia[i] * s[(size_t)i * D + d] + bias[d];
  int lane = d & 63, wid = d >> 6;
  if (MODE == 0) {
    float t = v;
    for (int off = 32; off > 0; off >>= 1) t += __shfl_down(t, off);
    if (lane == 0) red[wid] = t;
    __syncthreads();
    float mu = (red[0] + red[1]) * (1.f / 128.f);
    __syncthreads();
    float dv = v - mu;
    t = dv * dv;
    for (int off = 32; off > 0; off >>= 1) t += __shfl_down(t, off);
    if (lane == 0) red[wid] = t;
    __syncthreads();
    float var = (red[0] + red[1]) * (1.f / 128.f);
    float y = dv * rsqrtf(var + EPS) * g[d] + be[d];
    outF[(size_t)i * D + d] = fmaxf(y, 0.f);
  } else {
    float t = v;
    for (int off = 32; off > 0; off >>= 1) t = fmaxf(t, __shfl_down(t, off));
    if (lane == 0) red[wid] = t;
    __syncthreads();
    float m = fmaxf(red[0], red[1]);
    __syncthreads();
    t = expf(v - m);
    for (int off = 32; off > 0; off >>= 1) t += __shfl_down(t, off);
    if (lane == 0) red[wid] = t;
    __syncthreads();
    float l = logf(red[0] + red[1]);
    outF[(size_t)i * D + d] = v - m - l;
  }
}

extern "C" void kernel_launch(void* const* d_in, const int* in_sizes, int n_in,
                              void* d_out, int out_size, void* d_ws, size_t ws_size,
                              hipStream_t stream) {
  const float* x   = (const float*)d_in[0];
  const float* W0  = (const float*)d_in[1];
  const float* b0  = (const float*)d_in[2];
  const float* W1  = (const float*)d_in[3];
  const float* b1  = (const float*)d_in[4];
  const float* g1  = (const float*)d_in[5];
  const float* be1 = (const float*)d_in[6];
  const float* g2  = (const float*)d_in[7];
  const float* be2 = (const float*)d_in[8];
  const float* dW  = (const float*)d_in[9];
  const float* db  = (const float*)d_in[10];
  const int* row   = (const int*)d_in[11];
  const int* col   = (const int*)d_in[12];
  int N = in_sizes[0] / D;
  int E = in_sizes[11];
  float* out = (float*)d_out;

  float* base = (float*)d_ws;
  size_t off = 0;
  auto alloc = [&](size_t elems) {
    float* p = base + off;
    off += (elems + 3) & ~(size_t)3;   // keep 16B alignment
    return p;
  };
  size_t N128 = (size_t)N * D;
  int Npad = (N + 3) & ~3;
  float* hA   = alloc(N128);           // layer-0 output
  float* hB   = alloc(N128);           // layer-1 output
  float* hn   = alloc(N128);           // normalized h for sim
  float* s    = alloc(N128);           // h @ W
  int*   rowS = (int*)alloc(E);
  int*   colS = (int*)alloc(E);
  int*   rev  = (int*)alloc(E);
  float* simS = alloc(E);
  float* weS  = alloc(E);
  int*   cc   = (int*)alloc((size_t)2 * Npad);  // cnt | cur
  int*   cnt  = cc;
  int*   cur  = cc + Npad;
  int*   rptr = (int*)alloc(N + 1);
  float* rsE  = alloc(N);
  float* wdia = alloc(N);
  (void)ws_size; (void)n_in; (void)out_size;

  hipMemsetAsync(cc, 0, (size_t)2 * Npad * sizeof(int), stream);
  k_count<<<(E + 255) / 256, 256, 0, stream>>>(row, cnt, E);
  k_scan<<<1, 1024, 0, stream>>>(cnt, rptr, N, E);
  k_scatter<<<(E + 255) / 256, 256, 0, stream>>>(row, col, rptr, cur, rowS, colS, E);
  k_rev<<<(E + 255) / 256, 256, 0, stream>>>(rowS, colS, rptr, rev, E);

  auto layer = [&](const float* hin, float* hout, const float* Wf,
                   const float* bf, const float* gf, const float* bef, int mode) {
    k_normalize<<<(N + 7) / 8, 256, 0, stream>>>(hin, hn, N);
    k_sim<<<(E + 7) / 8, 256, 0, stream>>>(hn, rowS, colS, simS, E);
    k_rowsum<<<(N + 255) / 256, 256, 0, stream>>>(rptr, simS, rsE, N);
    k_drop<<<(N + 255) / 256, 256, 0, stream>>>(rptr, simS, rsE, colS, rev, weS,
                                                wdia, dW, db, N);
    k_gemm<<<(N + 63) / 64, 256, 0, stream>>>(hin, Wf, s, N);
    if (mode == 0)
      k_combine<0><<<N, 128, 0, stream>>>(s, weS, wdia, rptr, colS, bf, gf, bef,
                                          hout, N);
    else
      k_combine<1><<<N, 128, 0, stream>>>(s, weS, wdia, rptr, colS, bf, gf, bef,
                                          hout, N);
  };
  // layer 0: x -> hA (W0, b0, ln1)
  layer(x, hA, W0, b0, g1, be1, 0);
  // layer 1: hA -> hB (W1, b1, ln2)
  layer(hA, hB, W1, b1, g2, be2, 0);
  // final: hB -> out (W1, b1, log_softmax)  [source bug reuses convs[-2]]
  layer(hB, out, W1, b1, nullptr, nullptr, 1);
}

// Round 4
// 854.468 us; speedup vs baseline: 1.4115x; 1.0501x over previous
//
#include <hip/hip_runtime.h>
#include <hip/hip_bf16.h>

#define D 128
#define EPS 1e-5f

// ---------- CSR build (once per launch) ----------
__global__ __launch_bounds__(256) void k_count(const int* __restrict__ row,
                                               int* __restrict__ cnt, int E) {
  int e = blockIdx.x * 256 + threadIdx.x;
  if (e < E) atomicAdd(&cnt[row[e]], 1);
}

__global__ __launch_bounds__(1024) void k_scan(const int* __restrict__ cnt,
                                               int* __restrict__ rptr, int N, int E) {
  __shared__ int sh[1024];
  int t = threadIdx.x;
  int CH = (N + 1023) / 1024;
  int lo = t * CH, hi = min(N, lo + CH);
  int s = 0;
  for (int i = lo; i < hi; ++i) s += cnt[i];
  sh[t] = s;
  __syncthreads();
  for (int off = 1; off < 1024; off <<= 1) {
    int v = (t >= off) ? sh[t - off] : 0;
    __syncthreads();
    sh[t] += v;
    __syncthreads();
  }
  int run = (t > 0) ? sh[t - 1] : 0;
  for (int i = lo; i < hi; ++i) { rptr[i] = run; run += cnt[i]; }
  if (t == 0) rptr[N] = E;
}

__global__ __launch_bounds__(256) void k_scatter(
    const int* __restrict__ row, const int* __restrict__ col,
    const int* __restrict__ rptr, int* __restrict__ cur,
    int* __restrict__ rowS, int* __restrict__ colS, int E) {
  int e = blockIdx.x * 256 + threadIdx.x;
  if (e < E) {
    int r = row[e];
    int p = rptr[r] + atomicAdd(&cur[r], 1);
    rowS[p] = r;
    colS[p] = col[e];
  }
}

__global__ __launch_bounds__(256) void k_rev(const int* __restrict__ rowS,
                                             const int* __restrict__ colS,
                                             const int* __restrict__ rptr,
                                             int* __restrict__ rev, int E) {
  int p = blockIdx.x * 256 + threadIdx.x;
  if (p >= E) return;
  int r = rowS[p], c = colS[p];
  int q1 = rptr[c + 1];
  int rv = -1;
  for (int q = rptr[c]; q < q1; ++q)
    if (colS[q] == r) { rv = q; break; }
  rev[p] = rv;
}

// ---------- norms of input x (layers 1-2 get norms from combine epilogue) ----
__global__ __launch_bounds__(256) void k_norms(const float* __restrict__ h,
                                               float* __restrict__ nrm, int N) {
  int i = blockIdx.x * 8 + (threadIdx.x >> 5);
  int sub = threadIdx.x & 31;
  if (i >= N) return;
  float4 a = ((const float4*)(h + (size_t)i * D))[sub];
  float v = a.x * a.x + a.y * a.y + a.z * a.z + a.w * a.w;
  for (int off = 16; off > 0; off >>= 1) v += __shfl_down(v, off, 32);
  if (sub == 0) nrm[i] = sqrtf(v);
}

// ---------- node-centric sim + fused row-sum ----------
// one wave per node; 2 neighbors per iteration (32 lanes each).
__global__ __launch_bounds__(256) void k_sim(
    const float* __restrict__ h, const float* __restrict__ nrm,
    const int* __restrict__ rptr, const int* __restrict__ colS,
    float* __restrict__ simS, float* __restrict__ rsE, int N) {
  int i = blockIdx.x * 4 + (threadIdx.x >> 6);
  if (i >= N) return;
  int lane = threadIdx.x & 63;
  int sub = lane & 31;
  int half = lane >> 5;
  int p0 = rptr[i], p1 = rptr[i + 1];
  float4 ai = ((const float4*)(h + (size_t)i * D))[sub];
  float ni = nrm[i];
  float rs = 0.f;
  for (int base = p0; base < p1; base += 2) {
    int p = base + half;
    bool valid = p < p1;
    int c = valid ? colS[p] : i;
    float4 b = ((const float4*)(h + (size_t)c * D))[sub];
    float v = ai.x * b.x + ai.y * b.y + ai.z * b.z + ai.w * b.w;
    for (int off = 16; off > 0; off >>= 1) v += __shfl_down(v, off, 32);
    if (sub == 0 && valid) {
      float sm = v / (ni * nrm[c]);
      sm = (sm < 0.1f) ? 0.0f : sm;
      simS[p] = sm;
      rs += sm;
    }
  }
  // combine the two half-wave partial row sums (lanes 0 and 32)
  rs += __shfl_xor(rs, 32);
  if (lane == 0) rsE[i] = (rs > 0.f) ? rs : 1.f;
}

// ---------- s = h @ W (f32, BM=64, BN=128, 128 thr, 8x8/thread) ----------
__global__ __launch_bounds__(128) void k_gemm(const float* __restrict__ A,
                                              const float* __restrict__ W,
                                              float* __restrict__ S, int N) {
  __shared__ float As[64 * D];   // 32 KB
  __shared__ float Ws[64 * D];   // 32 KB (one K-phase of W)
  int t = threadIdx.x;
  int i0 = blockIdx.x * 64;
  // stage A tile (64x128) as float4
  for (int ch = 0; ch < 16; ++ch) {
    int q = t + 128 * ch;              // [0,2048) float4 slots
    int r = q >> 5, c4 = q & 31;
    int gi = i0 + r;
    float4 a4 = (gi < N) ? ((const float4*)(A + (size_t)gi * D))[c4]
                         : make_float4(0.f, 0.f, 0.f, 0.f);
    ((float4*)As)[q] = a4;
  }
  int tx = t & 15, ty = t >> 4;        // cols: [4tx..4tx+3] and [64+4tx..], rows: 8ty..8ty+7
  float acc[8][8] = {};
  for (int ph = 0; ph < 2; ++ph) {
    __syncthreads();
    for (int ch = 0; ch < 16; ++ch) {
      int q = t + 128 * ch;            // 64 W k-rows of this phase
      ((float4*)Ws)[q] = ((const float4*)(W + (size_t)ph * 64 * D))[q];
    }
    __syncthreads();
    for (int kk = 0; kk < 16; ++kk) {  // 4 k's per iter
      float4 a4[8];
#pragma unroll
      for (int r = 0; r < 8; ++r)
        a4[r] = ((const float4*)(As + (ty * 8 + r) * D))[ph * 16 + kk];
      float4 b0[4], b1[4];
#pragma unroll
      for (int k = 0; k < 4; ++k) {
        b0[k] = ((const float4*)(Ws + (kk * 4 + k) * D))[tx];
        b1[k] = ((const float4*)(Ws + (kk * 4 + k) * D))[16 + tx];
      }
#pragma unroll
      for (int r = 0; r < 8; ++r) {
        float4 a = a4[r];
#pragma unroll
        for (int c = 0; c < 4; ++c) {
          acc[r][c] += a.x * (&b0[0].x)[c] + a.y * (&b0[1].x)[c] +
                       a.z * (&b0[2].x)[c] + a.w * (&b0[3].x)[c];
          acc[r][4 + c] += a.x * (&b1[0].x)[c] + a.y * (&b1[1].x)[c] +
                           a.z * (&b1[2].x)[c] + a.w * (&b1[3].x)[c];
        }
      }
    }
  }
#pragma unroll
  for (int r = 0; r < 8; ++r) {
    int gi = i0 + ty * 8 + r;
    if (gi < N) {
      ((float4*)(S + (size_t)gi * D))[tx] =
          make_float4(acc[r][0], acc[r][1], acc[r][2], acc[r][3]);
      ((float4*)(S + (size_t)gi * D))[16 + tx] =
          make_float4(acc[r][4], acc[r][5], acc[r][6], acc[r][7]);
    }
  }
}

// ---------- fused: drop-mask + aggregate + self + bias + LN/ReLU or log_softmax
// MODE 0: LN+ReLU, writes hout and nrm for the next layer's sim.
// MODE 1: log_softmax.
template <int MODE>
__global__ __launch_bounds__(128) void k_combine(
    const float* __restrict__ s, const float* __restrict__ simS,
    const float* __restrict__ rsE, const int* __restrict__ rev,
    const int* __restrict__ rptr, const int* __restrict__ colS,
    const float* __restrict__ bias, const float* __restrict__ g,
    const float* __restrict__ be, const float* __restrict__ dWp,
    const float* __restrict__ dbp, float* __restrict__ outF,
    float* __restrict__ nrmOut, int N) {
  int i = blockIdx.x;
  int d = threadIdx.x;                 // 0..127
  __shared__ float red[2];
  __shared__ float sw[128];
  __shared__ int scl[128];
  __shared__ int scnt;
  float w0 = dWp[0], w1 = dWp[1], bd = dbp[0];
  int p0 = rptr[i], p1 = rptr[i + 1];
  float ri = rsE[i];
  float acc = 0.f;
  int deg = 0;
  for (int base = p0; base < p1; base += 128) {
    int m = min(128, p1 - base);
    if (d == 0) scnt = 0;
    __syncthreads();
    if (d < m) {
      int p = base + d;
      float sm = simS[p];
      if (sm != 0.f) {
        float a = sm / ri;
        int rv = rev[p];
        int c = colS[p];
        float ar = (rv >= 0) ? simS[rv] / rsE[c] : 0.f;
        float x = a * w0 + ar * w1 + bd;
        float sc = (x >= 0.f) ? 1.f / (1.f + expf(-x)) : expf(x) / (1.f + expf(x));
        if (sc > 0.5f) {
          int sl = atomicAdd(&scnt, 1);
          sw[sl] = expf(a);
          scl[sl] = c;
        }
      }
    }
    __syncthreads();
    int K = scnt;
    deg += K;
    int j = 0;
    for (; j + 4 <= K; j += 4) {
      int c0 = scl[j], c1 = scl[j + 1], c2 = scl[j + 2], c3 = scl[j + 3];
      float v0 = sw[j], v1 = sw[j + 1], v2 = sw[j + 2], v3 = sw[j + 3];
      float s0 = s[(size_t)c0 * D + d];
      float s1 = s[(size_t)c1 * D + d];
      float s2 = s[(size_t)c2 * D + d];
      float s3 = s[(size_t)c3 * D + d];
      acc += v0 * s0;
      acc += v1 * s1;
      acc += v2 * s2;
      acc += v3 * s3;
    }
    for (; j < K; ++j) acc += sw[j] * s[(size_t)scl[j] * D + d];
    __syncthreads();
  }
  float wd = expf(1.0f / (float)(deg + 1));
  float v = acc + wd * s[(size_t)i * D + d] + bias[d];
  int lane = d & 63, wid = d >> 6;
  if (MODE == 0) {
    float t = v;
    for (int off = 32; off > 0; off >>= 1) t += __shfl_down(t, off);
    if (lane == 0) red[wid] = t;
    __syncthreads();
    float mu = (red[0] + red[1]) * (1.f / 128.f);
    __syncthreads();
    float dv = v - mu;
    t = dv * dv;
    for (int off = 32; off > 0; off >>= 1) t += __shfl_down(t, off);
    if (lane == 0) red[wid] = t;
    __syncthreads();
    float var = (red[0] + red[1]) * (1.f / 128.f);
    float y = fmaxf(dv * rsqrtf(var + EPS) * g[d] + be[d], 0.f);
    outF[(size_t)i * D + d] = y;
    // fused next-layer row norm
    __syncthreads();
    t = y * y;
    for (int off = 32; off > 0; off >>= 1) t += __shfl_down(t, off);
    if (lane == 0) red[wid] = t;
    __syncthreads();
    if (d == 0) nrmOut[i] = sqrtf(red[0] + red[1]);
  } else {
    float t = v;
    for (int off = 32; off > 0; off >>= 1) t = fmaxf(t, __shfl_down(t, off));
    if (lane == 0) red[wid] = t;
    __syncthreads();
    float m = fmaxf(red[0], red[1]);
    __syncthreads();
    t = expf(v - m);
    for (int off = 32; off > 0; off >>= 1) t += __shfl_down(t, off);
    if (lane == 0) red[wid] = t;
    __syncthreads();
    float l = logf(red[0] + red[1]);
    outF[(size_t)i * D + d] = v - m - l;
  }
}

extern "C" void kernel_launch(void* const* d_in, const int* in_sizes, int n_in,
                              void* d_out, int out_size, void* d_ws, size_t ws_size,
                              hipStream_t stream) {
  const float* x   = (const float*)d_in[0];
  const float* W0  = (const float*)d_in[1];
  const float* b0  = (const float*)d_in[2];
  const float* W1  = (const float*)d_in[3];
  const float* b1  = (const float*)d_in[4];
  const float* g1  = (const float*)d_in[5];
  const float* be1 = (const float*)d_in[6];
  const float* g2  = (const float*)d_in[7];
  const float* be2 = (const float*)d_in[8];
  const float* dW  = (const float*)d_in[9];
  const float* db  = (const float*)d_in[10];
  const int* row   = (const int*)d_in[11];
  const int* col   = (const int*)d_in[12];
  int N = in_sizes[0] / D;
  int E = in_sizes[11];
  float* out = (float*)d_out;

  float* base = (float*)d_ws;
  size_t off = 0;
  auto alloc = [&](size_t elems) {
    float* p = base + off;
    off += (elems + 3) & ~(size_t)3;   // keep 16B alignment
    return p;
  };
  size_t N128 = (size_t)N * D;
  int Npad = (N + 3) & ~3;
  float* hA   = alloc(N128);           // layer-0 output
  float* hB   = alloc(N128);           // layer-1 output
  float* s    = alloc(N128);           // h @ W
  int*   rowS = (int*)alloc(E);
  int*   colS = (int*)alloc(E);
  int*   rev  = (int*)alloc(E);
  float* simS = alloc(E);
  int*   cc   = (int*)alloc((size_t)2 * Npad);  // cnt | cur
  int*   cnt  = cc;
  int*   cur  = cc + Npad;
  int*   rptr = (int*)alloc(N + 1);
  float* rsE  = alloc(N);
  float* nrm  = alloc(N);
  (void)ws_size; (void)n_in; (void)out_size;

  hipMemsetAsync(cc, 0, (size_t)2 * Npad * sizeof(int), stream);
  k_count<<<(E + 255) / 256, 256, 0, stream>>>(row, cnt, E);
  k_scan<<<1, 1024, 0, stream>>>(cnt, rptr, N, E);
  k_scatter<<<(E + 255) / 256, 256, 0, stream>>>(row, col, rptr, cur, rowS, colS, E);
  k_rev<<<(E + 255) / 256, 256, 0, stream>>>(rowS, colS, rptr, rev, E);
  k_norms<<<(N + 7) / 8, 256, 0, stream>>>(x, nrm, N);

  auto layer = [&](const float* hin, float* hout, const float* Wf,
                   const float* bf, const float* gf, const float* bef,
                   float* nrmOut, int mode) {
    k_sim<<<(N + 3) / 4, 256, 0, stream>>>(hin, nrm, rptr, colS, simS, rsE, N);
    k_gemm<<<(N + 63) / 64, 128, 0, stream>>>(hin, Wf, s, N);
    if (mode == 0)
      k_combine<0><<<N, 128, 0, stream>>>(s, simS, rsE, rev, rptr, colS, bf, gf,
                                          bef, dW, db, hout, nrmOut, N);
    else
      k_combine<1><<<N, 128, 0, stream>>>(s, simS, rsE, rev, rptr, colS, bf, gf,
                                          bef, dW, db, hout, nullptr, N);
  };
  // layer 0: x -> hA (W0, b0, ln1); writes nrm of hA
  layer(x, hA, W0, b0, g1, be1, nrm, 0);
  // layer 1: hA -> hB (W1, b1, ln2); writes nrm of hB
  layer(hA, hB, W1, b1, g2, be2, nrm, 0);
  // final: hB -> out (W1, b1, log_softmax)  [source bug reuses convs[-2]]
  layer(hB, out, W1, b1, nullptr, nullptr, nullptr, 1);
}

// Round 5
// 834.587 us; speedup vs baseline: 1.4451x; 1.0238x over previous
//
#include <hip/hip_runtime.h>
#include <hip/hip_bf16.h>

#define D 128
#define EPS 1e-5f

// ---------- CSR build (once per launch) ----------
__global__ __launch_bounds__(256) void k_count(const int* __restrict__ row,
                                               int* __restrict__ cnt, int E) {
  int e = blockIdx.x * 256 + threadIdx.x;
  if (e < E) atomicAdd(&cnt[row[e]], 1);
}

__global__ __launch_bounds__(1024) void k_scan(const int* __restrict__ cnt,
                                               int* __restrict__ rptr, int N, int E) {
  __shared__ int sh[1024];
  int t = threadIdx.x;
  int CH = (N + 1023) / 1024;
  int lo = t * CH, hi = min(N, lo + CH);
  int s = 0;
  for (int i = lo; i < hi; ++i) s += cnt[i];
  sh[t] = s;
  __syncthreads();
  for (int off = 1; off < 1024; off <<= 1) {
    int v = (t >= off) ? sh[t - off] : 0;
    __syncthreads();
    sh[t] += v;
    __syncthreads();
  }
  int run = (t > 0) ? sh[t - 1] : 0;
  for (int i = lo; i < hi; ++i) { rptr[i] = run; run += cnt[i]; }
  if (t == 0) rptr[N] = E;
}

__global__ __launch_bounds__(256) void k_scatter(
    const int* __restrict__ row, const int* __restrict__ col,
    const int* __restrict__ rptr, int* __restrict__ cur,
    int* __restrict__ rowS, int* __restrict__ colS, int E) {
  int e = blockIdx.x * 256 + threadIdx.x;
  if (e < E) {
    int r = row[e];
    int p = rptr[r] + atomicAdd(&cur[r], 1);
    rowS[p] = r;
    colS[p] = col[e];
  }
}

__global__ __launch_bounds__(256) void k_rev(const int* __restrict__ rowS,
                                             const int* __restrict__ colS,
                                             const int* __restrict__ rptr,
                                             int* __restrict__ rev, int E) {
  int p = blockIdx.x * 256 + threadIdx.x;
  if (p >= E) return;
  int r = rowS[p], c = colS[p];
  int q1 = rptr[c + 1];
  int rv = -1;
  for (int q = rptr[c]; q < q1; ++q)
    if (colS[q] == r) { rv = q; break; }
  rev[p] = rv;
}

// ---------- norms of input x (layers 1-2 get norms from combine epilogue) ----
__global__ __launch_bounds__(256) void k_norms(const float* __restrict__ h,
                                               float* __restrict__ nrm, int N) {
  int i = blockIdx.x * 8 + (threadIdx.x >> 5);
  int sub = threadIdx.x & 31;
  if (i >= N) return;
  float4 a = ((const float4*)(h + (size_t)i * D))[sub];
  float v = a.x * a.x + a.y * a.y + a.z * a.z + a.w * a.w;
  for (int off = 16; off > 0; off >>= 1) v += __shfl_down(v, off, 32);
  if (sub == 0) nrm[i] = sqrtf(v);
}

// ---------- node-centric sim + fused row-sum, 8 neighbors in flight ----------
__global__ __launch_bounds__(256) void k_sim(
    const float* __restrict__ h, const float* __restrict__ nrm,
    const int* __restrict__ rptr, const int* __restrict__ colS,
    float* __restrict__ simS, float* __restrict__ rsE, int N) {
  int i = blockIdx.x * 4 + (threadIdx.x >> 6);
  if (i >= N) return;
  int lane = threadIdx.x & 63;
  int sub = lane & 31;
  int half = lane >> 5;
  int p0 = rptr[i], p1 = rptr[i + 1];
  float4 ai = ((const float4*)(h + (size_t)i * D))[sub];
  float ni = nrm[i];
  float rs = 0.f;
  for (int base = p0; base < p1; base += 8) {
    int p[4], c[4];
    bool val[4];
    float4 b[4];
#pragma unroll
    for (int k = 0; k < 4; ++k) {
      p[k] = base + 2 * k + half;
      val[k] = p[k] < p1;
      c[k] = val[k] ? colS[p[k]] : i;
    }
#pragma unroll
    for (int k = 0; k < 4; ++k)
      b[k] = ((const float4*)(h + (size_t)c[k] * D))[sub];
#pragma unroll
    for (int k = 0; k < 4; ++k) {
      float v = ai.x * b[k].x + ai.y * b[k].y + ai.z * b[k].z + ai.w * b[k].w;
      for (int off = 16; off > 0; off >>= 1) v += __shfl_down(v, off, 32);
      if (sub == 0 && val[k]) {
        float sm = v / (ni * nrm[c[k]]);
        sm = (sm < 0.1f) ? 0.0f : sm;
        simS[p[k]] = sm;
        rs += sm;
      }
    }
  }
  // combine the two half-wave partial row sums (lanes 0 and 32)
  rs += __shfl_xor(rs, 32);
  if (lane == 0) rsE[i] = (rs > 0.f) ? rs : 1.f;
}

// ---------- s = h @ W (f32, BM=64, BN=128, 128 thr, 8x8/thread) ----------
__global__ __launch_bounds__(128) void k_gemm(const float* __restrict__ A,
                                              const float* __restrict__ W,
                                              float* __restrict__ S, int N) {
  __shared__ float As[64 * D];   // 32 KB
  __shared__ float Ws[64 * D];   // 32 KB (one K-phase of W)
  int t = threadIdx.x;
  int i0 = blockIdx.x * 64;
  for (int ch = 0; ch < 16; ++ch) {
    int q = t + 128 * ch;              // [0,2048) float4 slots
    int r = q >> 5, c4 = q & 31;
    int gi = i0 + r;
    float4 a4 = (gi < N) ? ((const float4*)(A + (size_t)gi * D))[c4]
                         : make_float4(0.f, 0.f, 0.f, 0.f);
    ((float4*)As)[q] = a4;
  }
  int tx = t & 15, ty = t >> 4;
  float acc[8][8] = {};
  for (int ph = 0; ph < 2; ++ph) {
    __syncthreads();
    for (int ch = 0; ch < 16; ++ch) {
      int q = t + 128 * ch;
      ((float4*)Ws)[q] = ((const float4*)(W + (size_t)ph * 64 * D))[q];
    }
    __syncthreads();
    for (int kk = 0; kk < 16; ++kk) {
      float4 a4[8];
#pragma unroll
      for (int r = 0; r < 8; ++r)
        a4[r] = ((const float4*)(As + (ty * 8 + r) * D))[ph * 16 + kk];
      float4 b0[4], b1[4];
#pragma unroll
      for (int k = 0; k < 4; ++k) {
        b0[k] = ((const float4*)(Ws + (kk * 4 + k) * D))[tx];
        b1[k] = ((const float4*)(Ws + (kk * 4 + k) * D))[16 + tx];
      }
#pragma unroll
      for (int r = 0; r < 8; ++r) {
        float4 a = a4[r];
#pragma unroll
        for (int c = 0; c < 4; ++c) {
          acc[r][c] += a.x * (&b0[0].x)[c] + a.y * (&b0[1].x)[c] +
                       a.z * (&b0[2].x)[c] + a.w * (&b0[3].x)[c];
          acc[r][4 + c] += a.x * (&b1[0].x)[c] + a.y * (&b1[1].x)[c] +
                           a.z * (&b1[2].x)[c] + a.w * (&b1[3].x)[c];
        }
      }
    }
  }
#pragma unroll
  for (int r = 0; r < 8; ++r) {
    int gi = i0 + ty * 8 + r;
    if (gi < N) {
      ((float4*)(S + (size_t)gi * D))[tx] =
          make_float4(acc[r][0], acc[r][1], acc[r][2], acc[r][3]);
      ((float4*)(S + (size_t)gi * D))[16 + tx] =
          make_float4(acc[r][4], acc[r][5], acc[r][6], acc[r][7]);
    }
  }
}

// ---------- fused: drop-mask + aggregate + self + bias + LN/ReLU or log_softmax
// 256 threads/node: 8 groups x 32 lanes, one edge per group per pass, float4
// gathers (8 rows in flight). Epilogue in lanes 0-31 (width-32 shuffles).
template <int MODE>
__global__ __launch_bounds__(256) void k_combine(
    const float* __restrict__ s, const float* __restrict__ simS,
    const float* __restrict__ rsE, const int* __restrict__ rev,
    const int* __restrict__ rptr, const int* __restrict__ colS,
    const float* __restrict__ bias, const float* __restrict__ g,
    const float* __restrict__ be, const float* __restrict__ dWp,
    const float* __restrict__ dbp, float* __restrict__ outF,
    float* __restrict__ nrmOut, int N) {
  int i = blockIdx.x;
  int t = threadIdx.x;
  int grp = t >> 5, sub = t & 31;
  __shared__ float sw[256];
  __shared__ int scl[256];
  __shared__ float accL[8 * 128];
  __shared__ int scnt;
  float w0 = dWp[0], w1 = dWp[1], bd = dbp[0];
  int p0 = rptr[i], p1 = rptr[i + 1];
  float ri = rsE[i];
  float4 acc = make_float4(0.f, 0.f, 0.f, 0.f);
  int deg = 0;
  for (int base = p0; base < p1; base += 256) {
    int m = min(256, p1 - base);
    if (t == 0) scnt = 0;
    __syncthreads();
    if (t < m) {
      int p = base + t;
      float sm = simS[p];
      if (sm != 0.f) {
        float a = sm / ri;
        int rv = rev[p];
        int c = colS[p];
        float ar = (rv >= 0) ? simS[rv] / rsE[c] : 0.f;
        float x = a * w0 + ar * w1 + bd;
        float sc = (x >= 0.f) ? 1.f / (1.f + expf(-x)) : expf(x) / (1.f + expf(x));
        if (sc > 0.5f) {
          int sl = atomicAdd(&scnt, 1);
          sw[sl] = expf(a);
          scl[sl] = c;
        }
      }
    }
    __syncthreads();
    int K = scnt;
    deg += K;
    for (int j = grp; j < K; j += 8) {
      int c = scl[j];
      float w = sw[j];
      float4 sv = ((const float4*)(s + (size_t)c * D))[sub];
      acc.x += w * sv.x; acc.y += w * sv.y;
      acc.z += w * sv.z; acc.w += w * sv.w;
    }
    __syncthreads();                   // sw/scl reused next chunk
  }
  ((float4*)accL)[grp * 32 + sub] = acc;
  __syncthreads();
  if (t < 32) {
    float4 tot = make_float4(0.f, 0.f, 0.f, 0.f);
#pragma unroll
    for (int gq = 0; gq < 8; ++gq) {
      float4 a4 = ((const float4*)accL)[gq * 32 + t];
      tot.x += a4.x; tot.y += a4.y; tot.z += a4.z; tot.w += a4.w;
    }
    float wd = expf(1.0f / (float)(deg + 1));
    float4 sv = ((const float4*)(s + (size_t)i * D))[t];
    float4 bb = ((const float4*)bias)[t];
    float4 v = make_float4(tot.x + wd * sv.x + bb.x, tot.y + wd * sv.y + bb.y,
                           tot.z + wd * sv.z + bb.z, tot.w + wd * sv.w + bb.w);
    if (MODE == 0) {
      float sm = v.x + v.y + v.z + v.w;
      for (int off = 16; off > 0; off >>= 1) sm += __shfl_down(sm, off, 32);
      float mu = __shfl(sm, 0, 32) * (1.f / 128.f);
      float4 dv = make_float4(v.x - mu, v.y - mu, v.z - mu, v.w - mu);
      float q = dv.x * dv.x + dv.y * dv.y + dv.z * dv.z + dv.w * dv.w;
      for (int off = 16; off > 0; off >>= 1) q += __shfl_down(q, off, 32);
      float var = __shfl(q, 0, 32) * (1.f / 128.f);
      float rstd = rsqrtf(var + EPS);
      float4 gg = ((const float4*)g)[t];
      float4 eb = ((const float4*)be)[t];
      float4 y = make_float4(fmaxf(dv.x * rstd * gg.x + eb.x, 0.f),
                             fmaxf(dv.y * rstd * gg.y + eb.y, 0.f),
                             fmaxf(dv.z * rstd * gg.z + eb.z, 0.f),
                             fmaxf(dv.w * rstd * gg.w + eb.w, 0.f));
      ((float4*)(outF + (size_t)i * D))[t] = y;
      float q2 = y.x * y.x + y.y * y.y + y.z * y.z + y.w * y.w;
      for (int off = 16; off > 0; off >>= 1) q2 += __shfl_down(q2, off, 32);
      if (t == 0) nrmOut[i] = sqrtf(q2);
    } else {
      float mx = fmaxf(fmaxf(v.x, v.y), fmaxf(v.z, v.w));
      for (int off = 16; off > 0; off >>= 1) mx = fmaxf(mx, __shfl_down(mx, off, 32));
      float m = __shfl(mx, 0, 32);
      float es = expf(v.x - m) + expf(v.y - m) + expf(v.z - m) + expf(v.w - m);
      for (int off = 16; off > 0; off >>= 1) es += __shfl_down(es, off, 32);
      float l = logf(__shfl(es, 0, 32)) + m;
      ((float4*)(outF + (size_t)i * D))[t] =
          make_float4(v.x - l, v.y - l, v.z - l, v.w - l);
    }
  }
}

extern "C" void kernel_launch(void* const* d_in, const int* in_sizes, int n_in,
                              void* d_out, int out_size, void* d_ws, size_t ws_size,
                              hipStream_t stream) {
  const float* x   = (const float*)d_in[0];
  const float* W0  = (const float*)d_in[1];
  const float* b0  = (const float*)d_in[2];
  const float* W1  = (const float*)d_in[3];
  const float* b1  = (const float*)d_in[4];
  const float* g1  = (const float*)d_in[5];
  const float* be1 = (const float*)d_in[6];
  const float* g2  = (const float*)d_in[7];
  const float* be2 = (const float*)d_in[8];
  const float* dW  = (const float*)d_in[9];
  const float* db  = (const float*)d_in[10];
  const int* row   = (const int*)d_in[11];
  const int* col   = (const int*)d_in[12];
  int N = in_sizes[0] / D;
  int E = in_sizes[11];
  float* out = (float*)d_out;

  float* base = (float*)d_ws;
  size_t off = 0;
  auto alloc = [&](size_t elems) {
    float* p = base + off;
    off += (elems + 3) & ~(size_t)3;
    return p;
  };
  size_t N128 = (size_t)N * D;
  int Npad = (N + 3) & ~3;
  float* hA   = alloc(N128);
  float* hB   = alloc(N128);
  float* s    = alloc(N128);
  int*   rowS = (int*)alloc(E);
  int*   colS = (int*)alloc(E);
  int*   rev  = (int*)alloc(E);
  float* simS = alloc(E);
  int*   cc   = (int*)alloc((size_t)2 * Npad);  // cnt | cur
  int*   cnt  = cc;
  int*   cur  = cc + Npad;
  int*   rptr = (int*)alloc(N + 1);
  float* rsE  = alloc(N);
  float* nrm  = alloc(N);
  (void)ws_size; (void)n_in; (void)out_size;

  hipMemsetAsync(cc, 0, (size_t)2 * Npad * sizeof(int), stream);
  k_count<<<(E + 255) / 256, 256, 0, stream>>>(row, cnt, E);
  k_scan<<<1, 1024, 0, stream>>>(cnt, rptr, N, E);
  k_scatter<<<(E + 255) / 256, 256, 0, stream>>>(row, col, rptr, cur, rowS, colS, E);
  k_rev<<<(E + 255) / 256, 256, 0, stream>>>(rowS, colS, rptr, rev, E);
  k_norms<<<(N + 7) / 8, 256, 0, stream>>>(x, nrm, N);

  auto layer = [&](const float* hin, float* hout, const float* Wf,
                   const float* bf, const float* gf, const float* bef,
                   float* nrmOut, int mode) {
    k_sim<<<(N + 3) / 4, 256, 0, stream>>>(hin, nrm, rptr, colS, simS, rsE, N);
    k_gemm<<<(N + 63) / 64, 128, 0, stream>>>(hin, Wf, s, N);
    if (mode == 0)
      k_combine<0><<<N, 256, 0, stream>>>(s, simS, rsE, rev, rptr, colS, bf, gf,
                                          bef, dW, db, hout, nrmOut, N);
    else
      k_combine<1><<<N, 256, 0, stream>>>(s, simS, rsE, rev, rptr, colS, bf, gf,
                                          bef, dW, db, hout, nullptr, N);
  };
  // layer 0: x -> hA (W0, b0, ln1); writes nrm of hA
  layer(x, hA, W0, b0, g1, be1, nrm, 0);
  // layer 1: hA -> hB (W1, b1, ln2); writes nrm of hB
  layer(hA, hB, W1, b1, g2, be2, nrm, 0);
  // final: hB -> out (W1, b1, log_softmax)  [source bug reuses convs[-2]]
  layer(hB, out, W1, b1, nullptr, nullptr, nullptr, 1);
}